// Round 7
// baseline (217.440 us; speedup 1.0000x reference)
//
#include <hip/hip_runtime.h>
#include <math.h>

#define NB 2
#define NQ 8192
#define NL 8192
#define NC 128
#define NKN 8
#define NF 512
#define MQ (NB*NQ)   // 16384 rows total (both batches)

typedef __attribute__((ext_vector_type(8))) short bf16x8;
typedef __attribute__((ext_vector_type(4))) float f32x4;

__device__ __forceinline__ unsigned short f2bf_u(float f){
    unsigned u = __float_as_uint(f);
    return (unsigned short)((u + 0x7FFFu + ((u>>16)&1u)) >> 16);
}
__device__ __forceinline__ float bf2f(unsigned short s){
    return __uint_as_float(((unsigned)s) << 16);
}

// ===========================================================================
// Radius top-8 via uniform spatial grid, 16^3 cells per batch. (unchanged)
// ===========================================================================

__device__ __forceinline__ int cell_coord(float x) {
    int c = (int)(x * 16.0f);
    return min(15, max(0, c));
}

__global__ __launch_bounds__(256) void grid_count_kernel(
    const float* __restrict__ kxyz, const unsigned char* __restrict__ pad,
    int* __restrict__ cnt)
{
    int t = blockIdx.x*256 + threadIdx.x;
    if (pad[t]) return;
    int bat = t >> 13;
    float x = kxyz[t*3+0], y = kxyz[t*3+1], z = kxyz[t*3+2];
    int cell = (cell_coord(z)*16 + cell_coord(y))*16 + cell_coord(x);
    atomicAdd(&cnt[bat*4096 + cell], 1);
}

__global__ __launch_bounds__(1024) void grid_scan_kernel(
    const int* __restrict__ cnt, int* __restrict__ cs)
{
    __shared__ int wsum[17];
    int t = threadIdx.x;
    int v[8]; int s = 0;
    #pragma unroll
    for (int k = 0; k < 8; ++k) { v[k] = s; s += cnt[t*8 + k]; }
    int lane = t & 63, w = t >> 6;
    int inc = s;
    #pragma unroll
    for (int d = 1; d < 64; d <<= 1) {
        int o = __shfl_up(inc, d);
        if (lane >= d) inc += o;
    }
    if (lane == 63) wsum[w] = inc;
    __syncthreads();
    if (t == 0) {
        int a = 0;
        for (int i = 0; i < 16; ++i) { int x = wsum[i]; wsum[i] = a; a += x; }
        wsum[16] = a;
    }
    __syncthreads();
    int base = wsum[w] + (inc - s);
    #pragma unroll
    for (int k = 0; k < 8; ++k) cs[t*8 + k] = base + v[k];
    if (t == 1023) cs[8192] = wsum[16];
}

__global__ __launch_bounds__(256) void grid_scatter_kernel(
    const float* __restrict__ kxyz, const unsigned char* __restrict__ pad,
    const int* __restrict__ cs, int* __restrict__ fill, float4* __restrict__ ro)
{
    int t = blockIdx.x*256 + threadIdx.x;
    if (pad[t]) return;
    int bat = t >> 13, i = t & 8191;
    float x = kxyz[t*3+0], y = kxyz[t*3+1], z = kxyz[t*3+2];
    int cell = bat*4096 + (cell_coord(z)*16 + cell_coord(y))*16 + cell_coord(x);
    int pos = cs[cell] + atomicAdd(&fill[cell], 1);
    ro[pos] = make_float4(x, y, z, __int_as_float(i));
}

__device__ __forceinline__ void insert8(float cd, int id, float dk[8], int ik[8]) {
    if (cd < dk[7]) {
        dk[7] = cd; ik[7] = id;
        #pragma unroll
        for (int r = 6; r >= 0; --r) {
            bool sw = dk[r+1] < dk[r];
            float td = dk[r]; int ti = ik[r];
            dk[r]   = sw ? dk[r+1] : dk[r];
            ik[r]   = sw ? ik[r+1] : ik[r];
            dk[r+1] = sw ? td : dk[r+1];
            ik[r+1] = sw ? ti : ik[r+1];
        }
    }
}

template<int W>
__device__ __forceinline__ void scan_block(int l, int cx, int cy, int cz,
    float qx, float qy, float qz, const int* __restrict__ CS,
    const float4* __restrict__ RO, float dk[8], int ik[8])
{
    const int D = 2*W + 1;
    int xs = max(0, cx - W), xe = min(15, cx + W);
    int nx = xe - xs + 1;
    for (int r = l; r < D*D; r += 8) {
        int dz = r / D - W, dy = r % D - W;
        int zz = cz + dz, yy = cy + dy;
        if ((unsigned)zz > 15u || (unsigned)yy > 15u) continue;
        int c0 = (zz*16 + yy)*16 + xs;
        int s = CS[c0], e = CS[c0 + nx];
        for (int p = s; p < e; ++p) {
            float4 v = RO[p];
            float dx = qx - v.x, dyv = qy - v.y, dzv = qz - v.z;
            float cd = dx*dx + dyv*dyv + dzv*dzv;
            insert8(cd, __float_as_int(v.w), dk, ik);
        }
    }
}

__device__ __forceinline__ void merge8(float dk[8], int ik[8]) {
    #pragma unroll
    for (int m = 1; m <= 4; m <<= 1) {
        float od[8]; int oi[8];
        #pragma unroll
        for (int r = 0; r < 8; ++r) {
            od[r] = __shfl_xor(dk[r], m);
            oi[r] = __shfl_xor(ik[r], m);
        }
        float nd[8]; int ni[8];
        #pragma unroll
        for (int r = 0; r < 8; ++r) {
            bool take = od[7-r] < dk[r];
            nd[r] = take ? od[7-r] : dk[r];
            ni[r] = take ? oi[7-r] : ik[r];
        }
        #pragma unroll
        for (int st = 4; st >= 1; st >>= 1) {
            #pragma unroll
            for (int r = 0; r < 8; ++r) {
                if ((r & st) == 0 && (r | st) < 8) {
                    int b = r | st;
                    bool sw = nd[b] < nd[r];
                    float td = nd[r]; int ti = ni[r];
                    nd[r] = sw ? nd[b] : nd[r];
                    ni[r] = sw ? ni[b] : ni[r];
                    nd[b] = sw ? td : nd[b];
                    ni[b] = sw ? ti : ni[b];
                }
            }
        }
        #pragma unroll
        for (int r = 0; r < 8; ++r) { dk[r] = nd[r]; ik[r] = ni[r]; }
    }
}

__global__ __launch_bounds__(256) void radius_grid_query_kernel(
    const float* __restrict__ qxyz, const int* __restrict__ cellstart,
    const float4* __restrict__ reorder, int* __restrict__ idxout)
{
    const int tid  = threadIdx.x;
    const int l    = tid & 7;
    const int qloc = tid >> 3;
    const int gq   = blockIdx.x*32 + qloc;
    const int bat  = gq >> 13;
    const float qx = qxyz[gq*3+0], qy = qxyz[gq*3+1], qz = qxyz[gq*3+2];
    const int cx = cell_coord(qx), cy = cell_coord(qy), cz = cell_coord(qz);
    const int* CS = cellstart + bat*4096;
    const float R2  = (float)(0.4*0.4);
    const float R2P = __uint_as_float(__float_as_uint(R2) + 1u);

    float dk[8]; int ik[8];
    #pragma unroll
    for (int r = 0; r < 8; ++r) { dk[r] = R2P; ik[r] = -1; }

    scan_block<2>(l, cx, cy, cz, qx, qy, qz, CS, reorder, dk, ik);
    merge8(dk, ik);
    bool done = dk[7] <= 0.015625f;

    if (!done) {
        #pragma unroll
        for (int r = 0; r < 8; ++r) { dk[r] = R2P; ik[r] = -1; }
        scan_block<4>(l, cx, cy, cz, qx, qy, qz, CS, reorder, dk, ik);
        merge8(dk, ik);
        done = dk[7] <= 0.0625f;
    }
    if (!done) {
        #pragma unroll
        for (int r = 0; r < 8; ++r) { dk[r] = R2P; ik[r] = -1; }
        scan_block<16>(l, cx, cy, cz, qx, qy, qz, CS, reorder, dk, ik);
        merge8(dk, ik);
    }

    if (l == 0) {
        int o[8];
        #pragma unroll
        for (int r = 0; r < 8; ++r) o[r] = (dk[r] <= R2) ? ik[r] : -1;
        int4 a = {o[0], o[1], o[2], o[3]};
        int4 b = {o[4], o[5], o[6], o[7]};
        *(int4*)&idxout[(size_t)gq*8 + 0] = a;
        *(int4*)&idxout[(size_t)gq*8 + 4] = b;
    }
}

// ===========================================================================
// Unified weight prep + grid zero (unchanged).
// ===========================================================================
__global__ __launch_bounds__(256) void prep_all_kernel(
    const float* __restrict__ posw2, const float* __restrict__ attnw,
    const float* __restrict__ lin_w, const float* __restrict__ lin_src_w,
    const float* __restrict__ lin_dst_w,
    const float* __restrict__ ffn_w1, const float* __restrict__ ffn_w2,
    unsigned short* __restrict__ imgb, int* __restrict__ zero_p)
{
    int t = blockIdx.x*256 + threadIdx.x;
    if (t < 16384) {
        int k = t >> 7, n = t & 127;
        imgb[(k >> 5)*4096 + n*32 + (k & 31)] = f2bf_u(posw2[t]);
    } else if (t < 32768) {
        int u = t - 16384;
        int k = u >> 7, n = u & 127;
        imgb[16384 + (k >> 5)*4096 + n*32 + (k & 31)] = f2bf_u(attnw[u]);
    } else if (t < 65536) {
        int u = t - 32768;
        int k = u >> 8, n = u & 255;
        float v = (n < 128) ? lin_w[k*128 + n] : lin_src_w[k*128 + (n-128)];
        imgb[32768 + ((k >> 5)*256 + n)*32 + (k & 31)] = f2bf_u(v);
    } else if (t < 81920) {
        int u = t - 65536;
        int k = u >> 7, n = u & 127;
        imgb[65536 + ((k >> 5)*128 + n)*32 + (k & 31)] = f2bf_u(lin_dst_w[u]);
    } else if (t < 147456) {
        int u = t - 81920;
        int k = u >> 9, n = u & 511;
        imgb[81920 + ((k >> 5)*512 + n)*32 + (k & 31)] = f2bf_u(ffn_w1[u]);
    } else if (t < 212992) {
        int u = t - 147456;
        int k = u >> 7, n = u & 127;
        imgb[147456 + ((k >> 5)*128 + n)*32 + (k & 31)] = f2bf_u(ffn_w2[u]);
    } else {
        zero_p[t - 212992] = 0;
    }
}

// ===========================================================================
// lin3 v2: y=0 computes BOTH vs halves (256 cols) per 64-row kv tile --
// kv_feat is read+staged ONCE instead of twice (saves 8.4MB HBM + half the
// sA staging/barrier cost). y=1 is the old q_feat @ lin_dst_w -> adst path.
// acc arrays statically indexed per-branch (no runtime-indexed ext_vector).
// ===========================================================================
__global__ __launch_bounds__(256) void lin3_kernel(
    const float* __restrict__ kv_feat, const float* __restrict__ q_feat,
    const unsigned short* __restrict__ wvs, const unsigned short* __restrict__ wd,
    unsigned short* __restrict__ vs, float* __restrict__ adst)
{
    __shared__ unsigned short sA[64*32];
    __shared__ unsigned short sB[256*32];
    const int tid = threadIdx.x;
    const int w = tid >> 6, lane = tid & 63, l15 = lane & 15, quad = lane >> 4;
    const int row0 = blockIdx.x*64;

    if (blockIdx.y == 0) {
        // ---- kv_feat @ [lin_w | lin_src_w] -> vs (bf16, 256 cols) ----
        f32x4 acc[16];
        #pragma unroll
        for (int t=0;t<16;t++){ acc[t][0]=0.f; acc[t][1]=0.f; acc[t][2]=0.f; acc[t][3]=0.f; }

        for (int kc = 0; kc < 4; ++kc) {
            __syncthreads();
            #pragma unroll
            for (int it = 0; it < 2; ++it) {
                int ix = it*256 + tid;
                int r = ix >> 3, kq = ix & 7;
                float4 a4 = *(const float4*)&kv_feat[(size_t)(row0+r)*NC + kc*32 + kq*4];
                ushort4 pk = { f2bf_u(a4.x), f2bf_u(a4.y), f2bf_u(a4.z), f2bf_u(a4.w) };
                *(ushort4*)&sA[r*32 + kq*4] = pk;
            }
            const int4* bsrc = (const int4*)(wvs + (size_t)kc*256*32);
            #pragma unroll
            for (int it = 0; it < 4; ++it) {
                int o = it*256 + tid;
                ((int4*)sB)[o] = bsrc[o];
            }
            __syncthreads();
            bf16x8 af = *(const bf16x8*)&sA[(w*16 + l15)*32 + quad*8];
            #pragma unroll
            for (int t = 0; t < 16; ++t) {
                bf16x8 bf = *(const bf16x8*)&sB[(16*t + l15)*32 + quad*8];
                acc[t] = __builtin_amdgcn_mfma_f32_16x16x32_bf16(af, bf, acc[t], 0, 0, 0);
            }
        }

        const int rowb = row0 + w*16 + quad*4;
        #pragma unroll
        for (int t = 0; t < 16; ++t) {
            int col = 16*t + l15;
            #pragma unroll
            for (int r = 0; r < 4; ++r)
                vs[(size_t)(rowb+r)*256 + col] = f2bf_u(acc[t][r]);
        }
    } else {
        // ---- q_feat @ lin_dst_w -> adst (fp32, 128 cols) ----
        f32x4 acc[8];
        #pragma unroll
        for (int t=0;t<8;t++){ acc[t][0]=0.f; acc[t][1]=0.f; acc[t][2]=0.f; acc[t][3]=0.f; }

        for (int kc = 0; kc < 4; ++kc) {
            __syncthreads();
            #pragma unroll
            for (int it = 0; it < 2; ++it) {
                int ix = it*256 + tid;
                int r = ix >> 3, kq = ix & 7;
                float4 a4 = *(const float4*)&q_feat[(size_t)(row0+r)*NC + kc*32 + kq*4];
                ushort4 pk = { f2bf_u(a4.x), f2bf_u(a4.y), f2bf_u(a4.z), f2bf_u(a4.w) };
                *(ushort4*)&sA[r*32 + kq*4] = pk;
            }
            const int4* bsrc = (const int4*)(wd + (size_t)kc*128*32);
            #pragma unroll
            for (int it = 0; it < 2; ++it) {
                int o = it*256 + tid;
                ((int4*)sB)[o] = bsrc[o];
            }
            __syncthreads();
            bf16x8 af = *(const bf16x8*)&sA[(w*16 + l15)*32 + quad*8];
            #pragma unroll
            for (int t = 0; t < 8; ++t) {
                bf16x8 bf = *(const bf16x8*)&sB[(16*t + l15)*32 + quad*8];
                acc[t] = __builtin_amdgcn_mfma_f32_16x16x32_bf16(af, bf, acc[t], 0, 0, 0);
            }
        }

        const int rowb = row0 + w*16 + quad*4;
        #pragma unroll
        for (int t = 0; t < 8; ++t) {
            int col = 16*t + l15;
            #pragma unroll
            for (int r = 0; r < 4; ++r)
                adst[(size_t)(rowb+r)*NC + col] = acc[t][r];
        }
    }
}

// ===========================================================================
// Fused FFN v4 (unchanged from round 5).
// ===========================================================================
__device__ inline float gelu_exact(float x) {
    return 0.5f*x*(1.0f + erff(x*0.7071067811865476f));
}

__global__ __launch_bounds__(256) void ffn_fused_kernel(
    const float* __restrict__ in1,
    const unsigned short* __restrict__ wf1, const unsigned short* __restrict__ wf2,
    const float* __restrict__ b1v, const float* __restrict__ b2v,
    const float* __restrict__ g, const float* __restrict__ bb,
    float* __restrict__ out)
{
    __shared__ unsigned short sH[8*16*136];   // [tile*4 + chunk] H tiles (34.8KB)
    __shared__ float4 sS[2][16];
    __shared__ float4 sQ[2][16];
    const int tid = threadIdx.x;
    const int w = tid >> 6, lane = tid & 63, l15 = lane & 15, quad = lane >> 4;
    const int row0 = blockIdx.x*32;

    bf16x8 af0[4], af1[4];
    {
        const float* arow0 = in1 + (size_t)(row0 + l15)*NC;
        const float* arow1 = in1 + (size_t)(row0 + 16 + l15)*NC;
        #pragma unroll
        for (int kk = 0; kk < 4; ++kk) {
            float4 a0 = *(const float4*)&arow0[kk*32 + quad*8];
            float4 a1 = *(const float4*)&arow0[kk*32 + quad*8 + 4];
            bf16x8 v;
            v[0]=(short)f2bf_u(a0.x); v[1]=(short)f2bf_u(a0.y);
            v[2]=(short)f2bf_u(a0.z); v[3]=(short)f2bf_u(a0.w);
            v[4]=(short)f2bf_u(a1.x); v[5]=(short)f2bf_u(a1.y);
            v[6]=(short)f2bf_u(a1.z); v[7]=(short)f2bf_u(a1.w);
            af0[kk] = v;
            float4 b0 = *(const float4*)&arow1[kk*32 + quad*8];
            float4 b1 = *(const float4*)&arow1[kk*32 + quad*8 + 4];
            bf16x8 u;
            u[0]=(short)f2bf_u(b0.x); u[1]=(short)f2bf_u(b0.y);
            u[2]=(short)f2bf_u(b0.z); u[3]=(short)f2bf_u(b0.w);
            u[4]=(short)f2bf_u(b1.x); u[5]=(short)f2bf_u(b1.y);
            u[6]=(short)f2bf_u(b1.z); u[7]=(short)f2bf_u(b1.w);
            af1[kk] = u;
        }
    }

    f32x4 acc1a[8], acc1b[8];
    #pragma unroll
    for (int t=0;t<8;t++){
        acc1a[t][0]=0.f; acc1a[t][1]=0.f; acc1a[t][2]=0.f; acc1a[t][3]=0.f;
        acc1b[t][0]=0.f; acc1b[t][1]=0.f; acc1b[t][2]=0.f; acc1b[t][3]=0.f;
    }
    #pragma unroll
    for (int kk=0;kk<4;kk++){
        #pragma unroll
        for (int t=0;t<8;t++){
            int n = w*128 + 16*t + l15;
            bf16x8 bf = *(const bf16x8*)&wf1[((size_t)kk*512 + n)*32 + quad*8];
            acc1a[t] = __builtin_amdgcn_mfma_f32_16x16x32_bf16(af0[kk], bf, acc1a[t], 0, 0, 0);
            acc1b[t] = __builtin_amdgcn_mfma_f32_16x16x32_bf16(af1[kk], bf, acc1b[t], 0, 0, 0);
        }
    }

    {
        unsigned short* Hw0 = sH + (w)*(16*136);
        unsigned short* Hw1 = sH + (4 + w)*(16*136);
        #pragma unroll
        for (int t=0;t<8;t++){
            float bv = b1v[w*128 + 16*t + l15];
            #pragma unroll
            for (int r=0;r<4;r++){
                float x0 = gelu_exact(acc1a[t][r] + bv);
                Hw0[(quad*4+r)*136 + 16*t + l15] = f2bf_u(x0);
                float x1 = gelu_exact(acc1b[t][r] + bv);
                Hw1[(quad*4+r)*136 + 16*t + l15] = f2bf_u(x1);
            }
        }
    }
    __syncthreads();

    f32x4 acc2a[2], acc2b[2];
    #pragma unroll
    for (int tt=0;tt<2;tt++){
        acc2a[tt][0]=0.f; acc2a[tt][1]=0.f; acc2a[tt][2]=0.f; acc2a[tt][3]=0.f;
        acc2b[tt][0]=0.f; acc2b[tt][1]=0.f; acc2b[tt][2]=0.f; acc2b[tt][3]=0.f;
    }
    #pragma unroll
    for (int kkg=0;kkg<16;kkg++){
        const unsigned short* Ht0 = sH + (kkg>>2)*(16*136);
        const unsigned short* Ht1 = sH + (4 + (kkg>>2))*(16*136);
        bf16x8 a2a = *(const bf16x8*)&Ht0[l15*136 + (kkg&3)*32 + quad*8];
        bf16x8 a2b = *(const bf16x8*)&Ht1[l15*136 + (kkg&3)*32 + quad*8];
        #pragma unroll
        for (int tt=0;tt<2;tt++){
            int col = (2*w+tt)*16 + l15;
            bf16x8 bf = *(const bf16x8*)&wf2[((size_t)kkg*128 + col)*32 + quad*8];
            acc2a[tt] = __builtin_amdgcn_mfma_f32_16x16x32_bf16(a2a, bf, acc2a[tt], 0, 0, 0);
            acc2b[tt] = __builtin_amdgcn_mfma_f32_16x16x32_bf16(a2b, bf, acc2b[tt], 0, 0, 0);
        }
    }

    float xv[2][2][4];
    float Ssum[2][4], Qsum[2][4];
    #pragma unroll
    for (int tile=0; tile<2; ++tile){
        #pragma unroll
        for (int r=0;r<4;r++){ Ssum[tile][r]=0.f; Qsum[tile][r]=0.f; }
        #pragma unroll
        for (int tt=0;tt<2;tt++){
            int col = (2*w+tt)*16 + l15;
            float bv = b2v[col];
            #pragma unroll
            for (int r=0;r<4;r++){
                int row = row0 + tile*16 + quad*4 + r;
                float a = (tile==0) ? acc2a[tt][r] : acc2b[tt][r];
                float x = a + bv + in1[(size_t)row*NC + col];
                xv[tile][tt][r] = x;
                Ssum[tile][r] += x; Qsum[tile][r] += x*x;
            }
        }
        #pragma unroll
        for (int m=1;m<=8;m<<=1){
            #pragma unroll
            for (int r=0;r<4;r++){
                Ssum[tile][r] += __shfl_xor(Ssum[tile][r], m);
                Qsum[tile][r] += __shfl_xor(Qsum[tile][r], m);
            }
        }
        if (l15 == 0){
            sS[tile][w*4 + quad] = make_float4(Ssum[tile][0],Ssum[tile][1],Ssum[tile][2],Ssum[tile][3]);
            sQ[tile][w*4 + quad] = make_float4(Qsum[tile][0],Qsum[tile][1],Qsum[tile][2],Qsum[tile][3]);
        }
    }
    __syncthreads();

    #pragma unroll
    for (int tile=0; tile<2; ++tile){
        float4 St = sS[tile][quad]; float4 Qt = sQ[tile][quad];
        {
            float4 a = sS[tile][4+quad],  b = sS[tile][8+quad],  c = sS[tile][12+quad];
            St.x += a.x+b.x+c.x; St.y += a.y+b.y+c.y; St.z += a.z+b.z+c.z; St.w += a.w+b.w+c.w;
            float4 d = sQ[tile][4+quad], e = sQ[tile][8+quad],  f = sQ[tile][12+quad];
            Qt.x += d.x+e.x+f.x; Qt.y += d.y+e.y+f.y; Qt.z += d.z+e.z+f.z; Qt.w += d.w+e.w+f.w;
        }
        float mean[4], rstd[4];
        {
            float sv[4] = {St.x, St.y, St.z, St.w};
            float qv[4] = {Qt.x, Qt.y, Qt.z, Qt.w};
            #pragma unroll
            for (int r=0;r<4;r++){
                float m_ = sv[r]*(1.f/128.f);
                float v_ = qv[r]*(1.f/128.f) - m_*m_;
                mean[r] = m_;
                rstd[r] = rsqrtf(v_ + 1e-5f);
            }
        }
        #pragma unroll
        for (int tt=0;tt<2;tt++){
            int col = (2*w+tt)*16 + l15;
            float gv = g[col], bv = bb[col];
            #pragma unroll
            for (int r=0;r<4;r++){
                int row = row0 + tile*16 + quad*4 + r;
                out[(size_t)row*NC + col] = (xv[tile][tt][r]-mean[r])*rstd[r]*gv + bv;
            }
        }
    }
}

// ===========================================================================
// Fused per-edge attention v5: v4 structure (512 thr, 8 waves, LDS weights)
// + h1-phase LDS reads vectorized: 128 ds_read_b32 -> 32 ds_read_b128
// (s_w1/s_b1 are 16B-aligned; the 8 c-values per kk are contiguous).
// ===========================================================================
__global__ __launch_bounds__(512) void attn_mfma_kernel(
    const float* __restrict__ qxyz, const float* __restrict__ qfeat,
    const float* __restrict__ kxyz,
    const float* __restrict__ posw1, const float* __restrict__ posb1,
    const float* __restrict__ posb2, const float* __restrict__ attnb,
    const float* __restrict__ ln1g, const float* __restrict__ ln1b,
    const unsigned short* __restrict__ wimg1, const unsigned short* __restrict__ wimg2,
    const int* __restrict__ idx, const unsigned short* __restrict__ vs,
    const float* __restrict__ adst, float* __restrict__ out1)
{
    __shared__ unsigned short s_w[16384];
    __shared__ unsigned short s_V[8*16*136];
    __shared__ unsigned short s_T[8*16*136];
    __shared__ __align__(16) float s_w1[384];
    __shared__ __align__(16) float s_b1[128];
    __shared__ float s_b2[128], s_ab[128], s_g[128], s_bb[128];
    __shared__ int   s_j[128];

    const int tid  = threadIdx.x;
    const int w    = tid >> 6;
    const int lane = tid & 63;
    const int l15  = lane & 15;
    const int quad = lane >> 4;
    const int qbase = blockIdx.x*16 + w*2;
    const int bat  = (blockIdx.x*16) >> 13;

    if (tid < 128) {
        s_b1[tid] = posb1[tid]; s_b2[tid] = posb2[tid];
        s_ab[tid] = attnb[tid]; s_g[tid] = ln1g[tid]; s_bb[tid] = ln1b[tid];
    } else if (tid < 256) {
        int i = tid - 128;
        s_w1[i] = posw1[i]; s_w1[128+i] = posw1[128+i]; s_w1[256+i] = posw1[256+i];
    }
    if (tid < 128) s_j[tid] = idx[(size_t)blockIdx.x*128 + tid];
    #pragma unroll
    for (int r = 0; r < 4; ++r)
        ((int4*)s_w)[r*512 + tid] = ((const int4*)wimg1)[r*512 + tid];
    __syncthreads();

    #pragma unroll
    for (int i = 0; i < 4; ++i) {
        int ix = lane + i*64;
        int el = ix >> 4, c16 = ix & 15;
        int j = s_j[w*16 + el];
        int jc = j < 0 ? 0 : j;
        const int4* rp = (const int4*)(vs + ((size_t)(bat*NL + jc))*256);
        int dst = (w*16 + el)*136 + c16*8;
        *(int4*)&s_V[dst] = rp[c16];
        *(int4*)&s_T[dst] = rp[16 + c16];
    }

    bf16x8 h1f[4];
    {
        int e  = w*16 + l15;
        int qh = qbase + (l15 >> 3);
        int j  = s_j[e];
        int jc = j < 0 ? 0 : j;
        const float* kp = kxyz + ((size_t)(bat*NL + jc))*3;
        float rx = qxyz[qh*3+0]-kp[0], ry = qxyz[qh*3+1]-kp[1], rz = qxyz[qh*3+2]-kp[2];
        #pragma unroll
        for (int kk=0;kk<4;kk++){
            int c0 = kk*32 + quad*8;
            #pragma unroll
            for (int h=0; h<2; ++h){
                float4 bb4 = *(const float4*)&s_b1[c0 + h*4];
                float4 wx4 = *(const float4*)&s_w1[c0 + h*4];
                float4 wy4 = *(const float4*)&s_w1[128 + c0 + h*4];
                float4 wz4 = *(const float4*)&s_w1[256 + c0 + h*4];
                float v0 = fmaxf(bb4.x + rx*wx4.x + ry*wy4.x + rz*wz4.x, 0.f);
                float v1 = fmaxf(bb4.y + rx*wx4.y + ry*wy4.y + rz*wz4.y, 0.f);
                float v2 = fmaxf(bb4.z + rx*wx4.z + ry*wy4.z + rz*wz4.z, 0.f);
                float v3 = fmaxf(bb4.w + rx*wx4.w + ry*wy4.w + rz*wz4.w, 0.f);
                h1f[kk][h*4+0] = (short)f2bf_u(v0);
                h1f[kk][h*4+1] = (short)f2bf_u(v1);
                h1f[kk][h*4+2] = (short)f2bf_u(v2);
                h1f[kk][h*4+3] = (short)f2bf_u(v3);
            }
        }
    }

    f32x4 acc[8];
    #pragma unroll
    for (int t=0;t<8;t++){ acc[t][0]=0.f; acc[t][1]=0.f; acc[t][2]=0.f; acc[t][3]=0.f; }
    #pragma unroll
    for (int kk=0;kk<4;kk++){
        #pragma unroll
        for (int t=0;t<8;t++){
            bf16x8 wf = *(const bf16x8*)&s_w[kk*4096 + (16*t + l15)*32 + quad*8];
            acc[t] = __builtin_amdgcn_mfma_f32_16x16x32_bf16(h1f[kk], wf, acc[t], 0, 0, 0);
        }
    }

    f32x4 dreg[8];
    #pragma unroll
    for (int t=0;t<8;t++){
        float b2v = s_b2[16*t + l15];
        #pragma unroll
        for (int r=0;r<4;r++) dreg[t][r] = fmaxf(acc[t][r] + b2v, 0.f);
    }

    bool val[4];
    #pragma unroll
    for (int r=0;r<4;r++){
        int j = s_j[w*16 + quad*4 + r];
        val[r] = (j >= 0);
    }
    const int qt = qbase + (quad >> 1);
    float ad[8];
    #pragma unroll
    for (int t=0;t<8;t++) ad[t] = adst[(size_t)qt*NC + 16*t + l15];

    __syncthreads();

    #pragma unroll
    for (int r = 0; r < 4; ++r)
        ((int4*)s_w)[r*512 + tid] = ((const int4*)wimg2)[r*512 + tid];

    {
        unsigned short* st = s_T + w*16*136;
        #pragma unroll
        for (int t=0;t<8;t++){
            #pragma unroll
            for (int r=0;r<4;r++){
                int o = (quad*4 + r)*136 + 16*t + l15;
                float sv = bf2f(st[o]);
                st[o] = f2bf_u(ad[t] - sv + dreg[t][r]);
            }
        }
    }
    __syncthreads();

    f32x4 acc2[8];
    #pragma unroll
    for (int t=0;t<8;t++){ acc2[t][0]=0.f; acc2[t][1]=0.f; acc2[t][2]=0.f; acc2[t][3]=0.f; }
    {
        const unsigned short* st = s_T + w*16*136;
        #pragma unroll
        for (int kk=0;kk<4;kk++){
            bf16x8 tf = *(const bf16x8*)&st[l15*136 + kk*32 + quad*8];
            #pragma unroll
            for (int t=0;t<8;t++){
                bf16x8 wf = *(const bf16x8*)&s_w[kk*4096 + (16*t + l15)*32 + quad*8];
                acc2[t] = __builtin_amdgcn_mfma_f32_16x16x32_bf16(tf, wf, acc2[t], 0, 0, 0);
            }
        }
    }

    float ex[8][4]; float dnm[8];
    #pragma unroll
    for (int t=0;t<8;t++){
        float ab = s_ab[16*t + l15];
        float s0 = val[0] ? fmaxf(acc2[t][0] + ab, 0.f) : -INFINITY;
        float s1 = val[1] ? fmaxf(acc2[t][1] + ab, 0.f) : -INFINITY;
        float s2 = val[2] ? fmaxf(acc2[t][2] + ab, 0.f) : -INFINITY;
        float s3 = val[3] ? fmaxf(acc2[t][3] + ab, 0.f) : -INFINITY;
        float mx = fmaxf(fmaxf(s0,s1), fmaxf(s2,s3));
        mx = fmaxf(mx, __shfl_xor(mx, 16));
        if (mx < -1e37f) mx = 0.f;
        ex[t][0] = __expf(s0 - mx);
        ex[t][1] = __expf(s1 - mx);
        ex[t][2] = __expf(s2 - mx);
        ex[t][3] = __expf(s3 - mx);
        float sm = ex[t][0]+ex[t][1]+ex[t][2]+ex[t][3];
        sm += __shfl_xor(sm, 16);
        dnm[t] = fmaxf(sm, 1e-12f);
    }

    float part[8];
    #pragma unroll
    for (int t=0;t<8;t++){
        float p = 0.f;
        #pragma unroll
        for (int r=0;r<4;r++){
            float vv = bf2f(s_V[(w*16 + quad*4 + r)*136 + 16*t + l15]);
            p += ex[t][r] * (vv + dreg[t][r]);
        }
        p += __shfl_xor(p, 16);
        part[t] = p / dnm[t];
    }

    float xln[8];
    float S = 0.f;
    #pragma unroll
    for (int t=0;t<8;t++){
        xln[t] = qfeat[(size_t)qt*NC + 16*t + l15] + part[t];
        S += xln[t];
    }
    #pragma unroll
    for (int m=1;m<=8;m<<=1) S += __shfl_xor(S, m);
    float mean = S * (1.f/128.f);
    float V = 0.f;
    #pragma unroll
    for (int t=0;t<8;t++){ float d = xln[t]-mean; V += d*d; }
    #pragma unroll
    for (int m=1;m<=8;m<<=1) V += __shfl_xor(V, m);
    float rstd = rsqrtf(V*(1.f/128.f) + 1e-5f);

    if ((quad & 1) == 0){
        #pragma unroll
        for (int t=0;t<8;t++){
            int c = 16*t + l15;
            out1[(size_t)qt*NC + c] = (xln[t]-mean)*rstd*s_g[c] + s_bb[c];
        }
    }
}

// ---------------------------------------------------------------------------
extern "C" void kernel_launch(void* const* d_in, const int* in_sizes, int n_in,
                              void* d_out, int out_size, void* d_ws, size_t ws_size,
                              hipStream_t stream)
{
    (void)in_sizes; (void)n_in; (void)out_size; (void)ws_size;
    const float* q_xyz   = (const float*)d_in[0];
    const float* q_feat  = (const float*)d_in[1];
    const float* kv_xyz  = (const float*)d_in[2];
    const float* kv_feat = (const float*)d_in[3];
    const unsigned char* kv_pad = (const unsigned char*)d_in[4];
    const float* pos_w1  = (const float*)d_in[5];
    const float* pos_b1  = (const float*)d_in[6];
    const float* pos_w2  = (const float*)d_in[7];
    const float* pos_b2  = (const float*)d_in[8];
    const float* attn_w  = (const float*)d_in[9];
    const float* attn_b  = (const float*)d_in[10];
    const float* lin_w   = (const float*)d_in[11];
    const float* lin_src_w = (const float*)d_in[12];
    const float* lin_dst_w = (const float*)d_in[13];
    const float* ln1_g   = (const float*)d_in[14];
    const float* ln1_b   = (const float*)d_in[15];
    const float* ffn_w1  = (const float*)d_in[16];
    const float* ffn_b1  = (const float*)d_in[17];
    const float* ffn_w2  = (const float*)d_in[18];
    const float* ffn_b2  = (const float*)d_in[19];
    const float* ln2_g   = (const float*)d_in[20];
    const float* ln2_b   = (const float*)d_in[21];

    float* ws    = (float*)d_ws;
    int*   idx   = (int*)d_ws;                                 // MQ*8 ints
    unsigned short* vs = (unsigned short*)(ws + 131072);       // [MQ,256] bf16 (v|s)
    float* adst  = ws + 131072 + 2*2097152;                    // [MQ,128] fp32
    float* out1  = adst + 2097152;                             // [MQ,128] fp32
    float* Hreg  = out1 + 2097152;                             // scratch region

    // grid-build scratch at Hreg start
    float4* reorder  = (float4*)Hreg;                // 256KB
    int* cellcnt   = (int*)(reorder + 16384);        // 8192
    int* cellfill  = cellcnt + 8192;                 // 8192
    int* cellstart = cellfill + 8192;                // 8193

    // weight images after grid scratch (offset 1MB into Hreg)
    unsigned short* imgb  = (unsigned short*)((char*)Hreg + (1u << 20));
    unsigned short* wimg1 = imgb;             // pos_w2    (16384)
    unsigned short* wimg2 = imgb + 16384;     // attn_w    (16384)
    unsigned short* wvs   = imgb + 32768;     // lin_w|lin_src_w (32768, Nd=256)
    unsigned short* wd    = imgb + 65536;     // lin_dst_w (16384)
    unsigned short* wf1   = imgb + 81920;     // ffn_w1    (65536, Nd=512)
    unsigned short* wf2   = imgb + 147456;    // ffn_w2    (65536)

    prep_all_kernel<<<dim3(896), dim3(256), 0, stream>>>(
        pos_w2, attn_w, lin_w, lin_src_w, lin_dst_w, ffn_w1, ffn_w2, imgb, cellcnt);

    grid_count_kernel<<<dim3(64), dim3(256), 0, stream>>>(kv_xyz, kv_pad, cellcnt);
    grid_scan_kernel<<<dim3(1), dim3(1024), 0, stream>>>(cellcnt, cellstart);
    grid_scatter_kernel<<<dim3(64), dim3(256), 0, stream>>>(kv_xyz, kv_pad, cellstart, cellfill, reorder);
    radius_grid_query_kernel<<<dim3(MQ/32), dim3(256), 0, stream>>>(q_xyz, cellstart, reorder, idx);

    lin3_kernel<<<dim3(MQ/64, 2), dim3(256), 0, stream>>>(kv_feat, q_feat, wvs, wd, vs, adst);

    attn_mfma_kernel<<<dim3(MQ/16), dim3(512), 0, stream>>>(
        q_xyz, q_feat, kv_xyz,
        pos_w1, pos_b1, pos_b2, attn_b, ln1_g, ln1_b,
        wimg1, wimg2, idx, vs, adst, out1);

    ffn_fused_kernel<<<dim3(MQ/32), dim3(256), 0, stream>>>(
        out1, wf1, wf2, ffn_b1, ffn_b2, ln2_g, ln2_b, (float*)d_out);
}

// Round 8
// 209.885 us; speedup vs baseline: 1.0360x; 1.0360x over previous
//
#include <hip/hip_runtime.h>
#include <math.h>

#define NB 2
#define NQ 8192
#define NL 8192
#define NC 128
#define NKN 8
#define NF 512
#define MQ (NB*NQ)   // 16384 rows total (both batches)

typedef __attribute__((ext_vector_type(8))) short bf16x8;
typedef __attribute__((ext_vector_type(4))) float f32x4;

__device__ __forceinline__ unsigned short f2bf_u(float f){
    unsigned u = __float_as_uint(f);
    return (unsigned short)((u + 0x7FFFu + ((u>>16)&1u)) >> 16);
}
__device__ __forceinline__ float bf2f(unsigned short s){
    return __uint_as_float(((unsigned)s) << 16);
}

// ===========================================================================
// Radius top-8 via uniform spatial grid, 16^3 cells per batch. (unchanged)
// ===========================================================================

__device__ __forceinline__ int cell_coord(float x) {
    int c = (int)(x * 16.0f);
    return min(15, max(0, c));
}

__global__ __launch_bounds__(256) void grid_count_kernel(
    const float* __restrict__ kxyz, const unsigned char* __restrict__ pad,
    int* __restrict__ cnt)
{
    int t = blockIdx.x*256 + threadIdx.x;
    if (pad[t]) return;
    int bat = t >> 13;
    float x = kxyz[t*3+0], y = kxyz[t*3+1], z = kxyz[t*3+2];
    int cell = (cell_coord(z)*16 + cell_coord(y))*16 + cell_coord(x);
    atomicAdd(&cnt[bat*4096 + cell], 1);
}

__global__ __launch_bounds__(1024) void grid_scan_kernel(
    const int* __restrict__ cnt, int* __restrict__ cs)
{
    __shared__ int wsum[17];
    int t = threadIdx.x;
    int v[8]; int s = 0;
    #pragma unroll
    for (int k = 0; k < 8; ++k) { v[k] = s; s += cnt[t*8 + k]; }
    int lane = t & 63, w = t >> 6;
    int inc = s;
    #pragma unroll
    for (int d = 1; d < 64; d <<= 1) {
        int o = __shfl_up(inc, d);
        if (lane >= d) inc += o;
    }
    if (lane == 63) wsum[w] = inc;
    __syncthreads();
    if (t == 0) {
        int a = 0;
        for (int i = 0; i < 16; ++i) { int x = wsum[i]; wsum[i] = a; a += x; }
        wsum[16] = a;
    }
    __syncthreads();
    int base = wsum[w] + (inc - s);
    #pragma unroll
    for (int k = 0; k < 8; ++k) cs[t*8 + k] = base + v[k];
    if (t == 1023) cs[8192] = wsum[16];
}

__global__ __launch_bounds__(256) void grid_scatter_kernel(
    const float* __restrict__ kxyz, const unsigned char* __restrict__ pad,
    const int* __restrict__ cs, int* __restrict__ fill, float4* __restrict__ ro)
{
    int t = blockIdx.x*256 + threadIdx.x;
    if (pad[t]) return;
    int bat = t >> 13, i = t & 8191;
    float x = kxyz[t*3+0], y = kxyz[t*3+1], z = kxyz[t*3+2];
    int cell = bat*4096 + (cell_coord(z)*16 + cell_coord(y))*16 + cell_coord(x);
    int pos = cs[cell] + atomicAdd(&fill[cell], 1);
    ro[pos] = make_float4(x, y, z, __int_as_float(i));
}

__device__ __forceinline__ void insert8(float cd, int id, float dk[8], int ik[8]) {
    if (cd < dk[7]) {
        dk[7] = cd; ik[7] = id;
        #pragma unroll
        for (int r = 6; r >= 0; --r) {
            bool sw = dk[r+1] < dk[r];
            float td = dk[r]; int ti = ik[r];
            dk[r]   = sw ? dk[r+1] : dk[r];
            ik[r]   = sw ? ik[r+1] : ik[r];
            dk[r+1] = sw ? td : dk[r+1];
            ik[r+1] = sw ? ti : ik[r+1];
        }
    }
}

template<int W>
__device__ __forceinline__ void scan_block(int l, int cx, int cy, int cz,
    float qx, float qy, float qz, const int* __restrict__ CS,
    const float4* __restrict__ RO, float dk[8], int ik[8])
{
    const int D = 2*W + 1;
    int xs = max(0, cx - W), xe = min(15, cx + W);
    int nx = xe - xs + 1;
    for (int r = l; r < D*D; r += 8) {
        int dz = r / D - W, dy = r % D - W;
        int zz = cz + dz, yy = cy + dy;
        if ((unsigned)zz > 15u || (unsigned)yy > 15u) continue;
        int c0 = (zz*16 + yy)*16 + xs;
        int s = CS[c0], e = CS[c0 + nx];
        for (int p = s; p < e; ++p) {
            float4 v = RO[p];
            float dx = qx - v.x, dyv = qy - v.y, dzv = qz - v.z;
            float cd = dx*dx + dyv*dyv + dzv*dzv;
            insert8(cd, __float_as_int(v.w), dk, ik);
        }
    }
}

__device__ __forceinline__ void merge8(float dk[8], int ik[8]) {
    #pragma unroll
    for (int m = 1; m <= 4; m <<= 1) {
        float od[8]; int oi[8];
        #pragma unroll
        for (int r = 0; r < 8; ++r) {
            od[r] = __shfl_xor(dk[r], m);
            oi[r] = __shfl_xor(ik[r], m);
        }
        float nd[8]; int ni[8];
        #pragma unroll
        for (int r = 0; r < 8; ++r) {
            bool take = od[7-r] < dk[r];
            nd[r] = take ? od[7-r] : dk[r];
            ni[r] = take ? oi[7-r] : ik[r];
        }
        #pragma unroll
        for (int st = 4; st >= 1; st >>= 1) {
            #pragma unroll
            for (int r = 0; r < 8; ++r) {
                if ((r & st) == 0 && (r | st) < 8) {
                    int b = r | st;
                    bool sw = nd[b] < nd[r];
                    float td = nd[r]; int ti = ni[r];
                    nd[r] = sw ? nd[b] : nd[r];
                    ni[r] = sw ? ni[b] : ni[r];
                    nd[b] = sw ? td : nd[b];
                    ni[b] = sw ? ti : ni[b];
                }
            }
        }
        #pragma unroll
        for (int r = 0; r < 8; ++r) { dk[r] = nd[r]; ik[r] = ni[r]; }
    }
}

// ===========================================================================
// MERGED kernel: radius query (blocks 0..511) + lin3 kv GEMM (512..767)
// + lin3 q GEMM (768..1023). The query path is latency-bound; the GEMM
// paths are MFMA-bound; running them co-resident fills each other's stalls
// and removes one full launch drain/ramp boundary. Bodies verbatim from
// the proven kernels. LDS = 20KB (GEMM staging; query blocks ignore it).
// ===========================================================================
__global__ __launch_bounds__(256) void query_lin3_kernel(
    const float* __restrict__ qxyz, const int* __restrict__ cellstart,
    const float4* __restrict__ reorder, int* __restrict__ idxout,
    const float* __restrict__ kv_feat, const float* __restrict__ q_feat,
    const unsigned short* __restrict__ wvs, const unsigned short* __restrict__ wd,
    unsigned short* __restrict__ vs, float* __restrict__ adst)
{
    __shared__ unsigned short sA[64*32];
    __shared__ unsigned short sB[256*32];
    const int tid = threadIdx.x;
    const int blk = blockIdx.x;

    if (blk < MQ/32) {
        // ---------------- radius top-8 query ----------------
        const int l    = tid & 7;
        const int qloc = tid >> 3;
        const int gq   = blk*32 + qloc;
        const int bat  = gq >> 13;
        const float qx = qxyz[gq*3+0], qy = qxyz[gq*3+1], qz = qxyz[gq*3+2];
        const int cx = cell_coord(qx), cy = cell_coord(qy), cz = cell_coord(qz);
        const int* CS = cellstart + bat*4096;
        const float R2  = (float)(0.4*0.4);
        const float R2P = __uint_as_float(__float_as_uint(R2) + 1u);

        float dk[8]; int ik[8];
        #pragma unroll
        for (int r = 0; r < 8; ++r) { dk[r] = R2P; ik[r] = -1; }

        scan_block<2>(l, cx, cy, cz, qx, qy, qz, CS, reorder, dk, ik);
        merge8(dk, ik);
        bool done = dk[7] <= 0.015625f;

        if (!done) {
            #pragma unroll
            for (int r = 0; r < 8; ++r) { dk[r] = R2P; ik[r] = -1; }
            scan_block<4>(l, cx, cy, cz, qx, qy, qz, CS, reorder, dk, ik);
            merge8(dk, ik);
            done = dk[7] <= 0.0625f;
        }
        if (!done) {
            #pragma unroll
            for (int r = 0; r < 8; ++r) { dk[r] = R2P; ik[r] = -1; }
            scan_block<16>(l, cx, cy, cz, qx, qy, qz, CS, reorder, dk, ik);
            merge8(dk, ik);
        }

        if (l == 0) {
            int o[8];
            #pragma unroll
            for (int r = 0; r < 8; ++r) o[r] = (dk[r] <= R2) ? ik[r] : -1;
            int4 a = {o[0], o[1], o[2], o[3]};
            int4 b = {o[4], o[5], o[6], o[7]};
            *(int4*)&idxout[(size_t)gq*8 + 0] = a;
            *(int4*)&idxout[(size_t)gq*8 + 4] = b;
        }
    } else if (blk < MQ/32 + MQ/64) {
        // ---------------- kv_feat @ [lin_w | lin_src_w] -> vs ----------------
        const int w = tid >> 6, lane = tid & 63, l15 = lane & 15, quad = lane >> 4;
        const int row0 = (blk - MQ/32)*64;

        f32x4 acc[16];
        #pragma unroll
        for (int t=0;t<16;t++){ acc[t][0]=0.f; acc[t][1]=0.f; acc[t][2]=0.f; acc[t][3]=0.f; }

        for (int kc = 0; kc < 4; ++kc) {
            __syncthreads();
            #pragma unroll
            for (int it = 0; it < 2; ++it) {
                int ix = it*256 + tid;
                int r = ix >> 3, kq = ix & 7;
                float4 a4 = *(const float4*)&kv_feat[(size_t)(row0+r)*NC + kc*32 + kq*4];
                ushort4 pk = { f2bf_u(a4.x), f2bf_u(a4.y), f2bf_u(a4.z), f2bf_u(a4.w) };
                *(ushort4*)&sA[r*32 + kq*4] = pk;
            }
            const int4* bsrc = (const int4*)(wvs + (size_t)kc*256*32);
            #pragma unroll
            for (int it = 0; it < 4; ++it) {
                int o = it*256 + tid;
                ((int4*)sB)[o] = bsrc[o];
            }
            __syncthreads();
            bf16x8 af = *(const bf16x8*)&sA[(w*16 + l15)*32 + quad*8];
            #pragma unroll
            for (int t = 0; t < 16; ++t) {
                bf16x8 bf = *(const bf16x8*)&sB[(16*t + l15)*32 + quad*8];
                acc[t] = __builtin_amdgcn_mfma_f32_16x16x32_bf16(af, bf, acc[t], 0, 0, 0);
            }
        }

        const int rowb = row0 + w*16 + quad*4;
        #pragma unroll
        for (int t = 0; t < 16; ++t) {
            int col = 16*t + l15;
            #pragma unroll
            for (int r = 0; r < 4; ++r)
                vs[(size_t)(rowb+r)*256 + col] = f2bf_u(acc[t][r]);
        }
    } else {
        // ---------------- q_feat @ lin_dst_w -> adst ----------------
        const int w = tid >> 6, lane = tid & 63, l15 = lane & 15, quad = lane >> 4;
        const int row0 = (blk - MQ/32 - MQ/64)*64;

        f32x4 acc[8];
        #pragma unroll
        for (int t=0;t<8;t++){ acc[t][0]=0.f; acc[t][1]=0.f; acc[t][2]=0.f; acc[t][3]=0.f; }

        for (int kc = 0; kc < 4; ++kc) {
            __syncthreads();
            #pragma unroll
            for (int it = 0; it < 2; ++it) {
                int ix = it*256 + tid;
                int r = ix >> 3, kq = ix & 7;
                float4 a4 = *(const float4*)&q_feat[(size_t)(row0+r)*NC + kc*32 + kq*4];
                ushort4 pk = { f2bf_u(a4.x), f2bf_u(a4.y), f2bf_u(a4.z), f2bf_u(a4.w) };
                *(ushort4*)&sA[r*32 + kq*4] = pk;
            }
            const int4* bsrc = (const int4*)(wd + (size_t)kc*128*32);
            #pragma unroll
            for (int it = 0; it < 2; ++it) {
                int o = it*256 + tid;
                ((int4*)sB)[o] = bsrc[o];
            }
            __syncthreads();
            bf16x8 af = *(const bf16x8*)&sA[(w*16 + l15)*32 + quad*8];
            #pragma unroll
            for (int t = 0; t < 8; ++t) {
                bf16x8 bf = *(const bf16x8*)&sB[(16*t + l15)*32 + quad*8];
                acc[t] = __builtin_amdgcn_mfma_f32_16x16x32_bf16(af, bf, acc[t], 0, 0, 0);
            }
        }

        const int rowb = row0 + w*16 + quad*4;
        #pragma unroll
        for (int t = 0; t < 8; ++t) {
            int col = 16*t + l15;
            #pragma unroll
            for (int r = 0; r < 4; ++r)
                adst[(size_t)(rowb+r)*NC + col] = acc[t][r];
        }
    }
}

// ===========================================================================
// Unified weight prep + grid zero (unchanged).
// ===========================================================================
__global__ __launch_bounds__(256) void prep_all_kernel(
    const float* __restrict__ posw2, const float* __restrict__ attnw,
    const float* __restrict__ lin_w, const float* __restrict__ lin_src_w,
    const float* __restrict__ lin_dst_w,
    const float* __restrict__ ffn_w1, const float* __restrict__ ffn_w2,
    unsigned short* __restrict__ imgb, int* __restrict__ zero_p)
{
    int t = blockIdx.x*256 + threadIdx.x;
    if (t < 16384) {
        int k = t >> 7, n = t & 127;
        imgb[(k >> 5)*4096 + n*32 + (k & 31)] = f2bf_u(posw2[t]);
    } else if (t < 32768) {
        int u = t - 16384;
        int k = u >> 7, n = u & 127;
        imgb[16384 + (k >> 5)*4096 + n*32 + (k & 31)] = f2bf_u(attnw[u]);
    } else if (t < 65536) {
        int u = t - 32768;
        int k = u >> 8, n = u & 255;
        float v = (n < 128) ? lin_w[k*128 + n] : lin_src_w[k*128 + (n-128)];
        imgb[32768 + ((k >> 5)*256 + n)*32 + (k & 31)] = f2bf_u(v);
    } else if (t < 81920) {
        int u = t - 65536;
        int k = u >> 7, n = u & 127;
        imgb[65536 + ((k >> 5)*128 + n)*32 + (k & 31)] = f2bf_u(lin_dst_w[u]);
    } else if (t < 147456) {
        int u = t - 81920;
        int k = u >> 9, n = u & 511;
        imgb[81920 + ((k >> 5)*512 + n)*32 + (k & 31)] = f2bf_u(ffn_w1[u]);
    } else if (t < 212992) {
        int u = t - 147456;
        int k = u >> 7, n = u & 127;
        imgb[147456 + ((k >> 5)*128 + n)*32 + (k & 31)] = f2bf_u(ffn_w2[u]);
    } else {
        zero_p[t - 212992] = 0;
    }
}

// ===========================================================================
// Fused FFN v4 (unchanged).
// ===========================================================================
__device__ inline float gelu_exact(float x) {
    return 0.5f*x*(1.0f + erff(x*0.7071067811865476f));
}

__global__ __launch_bounds__(256) void ffn_fused_kernel(
    const float* __restrict__ in1,
    const unsigned short* __restrict__ wf1, const unsigned short* __restrict__ wf2,
    const float* __restrict__ b1v, const float* __restrict__ b2v,
    const float* __restrict__ g, const float* __restrict__ bb,
    float* __restrict__ out)
{
    __shared__ unsigned short sH[8*16*136];   // [tile*4 + chunk] H tiles (34.8KB)
    __shared__ float4 sS[2][16];
    __shared__ float4 sQ[2][16];
    const int tid = threadIdx.x;
    const int w = tid >> 6, lane = tid & 63, l15 = lane & 15, quad = lane >> 4;
    const int row0 = blockIdx.x*32;

    bf16x8 af0[4], af1[4];
    {
        const float* arow0 = in1 + (size_t)(row0 + l15)*NC;
        const float* arow1 = in1 + (size_t)(row0 + 16 + l15)*NC;
        #pragma unroll
        for (int kk = 0; kk < 4; ++kk) {
            float4 a0 = *(const float4*)&arow0[kk*32 + quad*8];
            float4 a1 = *(const float4*)&arow0[kk*32 + quad*8 + 4];
            bf16x8 v;
            v[0]=(short)f2bf_u(a0.x); v[1]=(short)f2bf_u(a0.y);
            v[2]=(short)f2bf_u(a0.z); v[3]=(short)f2bf_u(a0.w);
            v[4]=(short)f2bf_u(a1.x); v[5]=(short)f2bf_u(a1.y);
            v[6]=(short)f2bf_u(a1.z); v[7]=(short)f2bf_u(a1.w);
            af0[kk] = v;
            float4 b0 = *(const float4*)&arow1[kk*32 + quad*8];
            float4 b1 = *(const float4*)&arow1[kk*32 + quad*8 + 4];
            bf16x8 u;
            u[0]=(short)f2bf_u(b0.x); u[1]=(short)f2bf_u(b0.y);
            u[2]=(short)f2bf_u(b0.z); u[3]=(short)f2bf_u(b0.w);
            u[4]=(short)f2bf_u(b1.x); u[5]=(short)f2bf_u(b1.y);
            u[6]=(short)f2bf_u(b1.z); u[7]=(short)f2bf_u(b1.w);
            af1[kk] = u;
        }
    }

    f32x4 acc1a[8], acc1b[8];
    #pragma unroll
    for (int t=0;t<8;t++){
        acc1a[t][0]=0.f; acc1a[t][1]=0.f; acc1a[t][2]=0.f; acc1a[t][3]=0.f;
        acc1b[t][0]=0.f; acc1b[t][1]=0.f; acc1b[t][2]=0.f; acc1b[t][3]=0.f;
    }
    #pragma unroll
    for (int kk=0;kk<4;kk++){
        #pragma unroll
        for (int t=0;t<8;t++){
            int n = w*128 + 16*t + l15;
            bf16x8 bf = *(const bf16x8*)&wf1[((size_t)kk*512 + n)*32 + quad*8];
            acc1a[t] = __builtin_amdgcn_mfma_f32_16x16x32_bf16(af0[kk], bf, acc1a[t], 0, 0, 0);
            acc1b[t] = __builtin_amdgcn_mfma_f32_16x16x32_bf16(af1[kk], bf, acc1b[t], 0, 0, 0);
        }
    }

    {
        unsigned short* Hw0 = sH + (w)*(16*136);
        unsigned short* Hw1 = sH + (4 + w)*(16*136);
        #pragma unroll
        for (int t=0;t<8;t++){
            float bv = b1v[w*128 + 16*t + l15];
            #pragma unroll
            for (int r=0;r<4;r++){
                float x0 = gelu_exact(acc1a[t][r] + bv);
                Hw0[(quad*4+r)*136 + 16*t + l15] = f2bf_u(x0);
                float x1 = gelu_exact(acc1b[t][r] + bv);
                Hw1[(quad*4+r)*136 + 16*t + l15] = f2bf_u(x1);
            }
        }
    }
    __syncthreads();

    f32x4 acc2a[2], acc2b[2];
    #pragma unroll
    for (int tt=0;tt<2;tt++){
        acc2a[tt][0]=0.f; acc2a[tt][1]=0.f; acc2a[tt][2]=0.f; acc2a[tt][3]=0.f;
        acc2b[tt][0]=0.f; acc2b[tt][1]=0.f; acc2b[tt][2]=0.f; acc2b[tt][3]=0.f;
    }
    #pragma unroll
    for (int kkg=0;kkg<16;kkg++){
        const unsigned short* Ht0 = sH + (kkg>>2)*(16*136);
        const unsigned short* Ht1 = sH + (4 + (kkg>>2))*(16*136);
        bf16x8 a2a = *(const bf16x8*)&Ht0[l15*136 + (kkg&3)*32 + quad*8];
        bf16x8 a2b = *(const bf16x8*)&Ht1[l15*136 + (kkg&3)*32 + quad*8];
        #pragma unroll
        for (int tt=0;tt<2;tt++){
            int col = (2*w+tt)*16 + l15;
            bf16x8 bf = *(const bf16x8*)&wf2[((size_t)kkg*128 + col)*32 + quad*8];
            acc2a[tt] = __builtin_amdgcn_mfma_f32_16x16x32_bf16(a2a, bf, acc2a[tt], 0, 0, 0);
            acc2b[tt] = __builtin_amdgcn_mfma_f32_16x16x32_bf16(a2b, bf, acc2b[tt], 0, 0, 0);
        }
    }

    float xv[2][2][4];
    float Ssum[2][4], Qsum[2][4];
    #pragma unroll
    for (int tile=0; tile<2; ++tile){
        #pragma unroll
        for (int r=0;r<4;r++){ Ssum[tile][r]=0.f; Qsum[tile][r]=0.f; }
        #pragma unroll
        for (int tt=0;tt<2;tt++){
            int col = (2*w+tt)*16 + l15;
            float bv = b2v[col];
            #pragma unroll
            for (int r=0;r<4;r++){
                int row = row0 + tile*16 + quad*4 + r;
                float a = (tile==0) ? acc2a[tt][r] : acc2b[tt][r];
                float x = a + bv + in1[(size_t)row*NC + col];
                xv[tile][tt][r] = x;
                Ssum[tile][r] += x; Qsum[tile][r] += x*x;
            }
        }
        #pragma unroll
        for (int m=1;m<=8;m<<=1){
            #pragma unroll
            for (int r=0;r<4;r++){
                Ssum[tile][r] += __shfl_xor(Ssum[tile][r], m);
                Qsum[tile][r] += __shfl_xor(Qsum[tile][r], m);
            }
        }
        if (l15 == 0){
            sS[tile][w*4 + quad] = make_float4(Ssum[tile][0],Ssum[tile][1],Ssum[tile][2],Ssum[tile][3]);
            sQ[tile][w*4 + quad] = make_float4(Qsum[tile][0],Qsum[tile][1],Qsum[tile][2],Qsum[tile][3]);
        }
    }
    __syncthreads();

    #pragma unroll
    for (int tile=0; tile<2; ++tile){
        float4 St = sS[tile][quad]; float4 Qt = sQ[tile][quad];
        {
            float4 a = sS[tile][4+quad],  b = sS[tile][8+quad],  c = sS[tile][12+quad];
            St.x += a.x+b.x+c.x; St.y += a.y+b.y+c.y; St.z += a.z+b.z+c.z; St.w += a.w+b.w+c.w;
            float4 d = sQ[tile][4+quad], e = sQ[tile][8+quad],  f = sQ[tile][12+quad];
            Qt.x += d.x+e.x+f.x; Qt.y += d.y+e.y+f.y; Qt.z += d.z+e.z+f.z; Qt.w += d.w+e.w+f.w;
        }
        float mean[4], rstd[4];
        {
            float sv[4] = {St.x, St.y, St.z, St.w};
            float qv[4] = {Qt.x, Qt.y, Qt.z, Qt.w};
            #pragma unroll
            for (int r=0;r<4;r++){
                float m_ = sv[r]*(1.f/128.f);
                float v_ = qv[r]*(1.f/128.f) - m_*m_;
                mean[r] = m_;
                rstd[r] = rsqrtf(v_ + 1e-5f);
            }
        }
        #pragma unroll
        for (int tt=0;tt<2;tt++){
            int col = (2*w+tt)*16 + l15;
            float gv = g[col], bv = bb[col];
            #pragma unroll
            for (int r=0;r<4;r++){
                int row = row0 + tile*16 + quad*4 + r;
                out[(size_t)row*NC + col] = (xv[tile][tt][r]-mean[r])*rstd[r]*gv + bv;
            }
        }
    }
}

// ===========================================================================
// Fused per-edge attention v5 (unchanged from round 6).
// ===========================================================================
__global__ __launch_bounds__(512) void attn_mfma_kernel(
    const float* __restrict__ qxyz, const float* __restrict__ qfeat,
    const float* __restrict__ kxyz,
    const float* __restrict__ posw1, const float* __restrict__ posb1,
    const float* __restrict__ posb2, const float* __restrict__ attnb,
    const float* __restrict__ ln1g, const float* __restrict__ ln1b,
    const unsigned short* __restrict__ wimg1, const unsigned short* __restrict__ wimg2,
    const int* __restrict__ idx, const unsigned short* __restrict__ vs,
    const float* __restrict__ adst, float* __restrict__ out1)
{
    __shared__ unsigned short s_w[16384];
    __shared__ unsigned short s_V[8*16*136];
    __shared__ unsigned short s_T[8*16*136];
    __shared__ __align__(16) float s_w1[384];
    __shared__ __align__(16) float s_b1[128];
    __shared__ float s_b2[128], s_ab[128], s_g[128], s_bb[128];
    __shared__ int   s_j[128];

    const int tid  = threadIdx.x;
    const int w    = tid >> 6;
    const int lane = tid & 63;
    const int l15  = lane & 15;
    const int quad = lane >> 4;
    const int qbase = blockIdx.x*16 + w*2;
    const int bat  = (blockIdx.x*16) >> 13;

    if (tid < 128) {
        s_b1[tid] = posb1[tid]; s_b2[tid] = posb2[tid];
        s_ab[tid] = attnb[tid]; s_g[tid] = ln1g[tid]; s_bb[tid] = ln1b[tid];
    } else if (tid < 256) {
        int i = tid - 128;
        s_w1[i] = posw1[i]; s_w1[128+i] = posw1[128+i]; s_w1[256+i] = posw1[256+i];
    }
    if (tid < 128) s_j[tid] = idx[(size_t)blockIdx.x*128 + tid];
    #pragma unroll
    for (int r = 0; r < 4; ++r)
        ((int4*)s_w)[r*512 + tid] = ((const int4*)wimg1)[r*512 + tid];
    __syncthreads();

    #pragma unroll
    for (int i = 0; i < 4; ++i) {
        int ix = lane + i*64;
        int el = ix >> 4, c16 = ix & 15;
        int j = s_j[w*16 + el];
        int jc = j < 0 ? 0 : j;
        const int4* rp = (const int4*)(vs + ((size_t)(bat*NL + jc))*256);
        int dst = (w*16 + el)*136 + c16*8;
        *(int4*)&s_V[dst] = rp[c16];
        *(int4*)&s_T[dst] = rp[16 + c16];
    }

    bf16x8 h1f[4];
    {
        int e  = w*16 + l15;
        int qh = qbase + (l15 >> 3);
        int j  = s_j[e];
        int jc = j < 0 ? 0 : j;
        const float* kp = kxyz + ((size_t)(bat*NL + jc))*3;
        float rx = qxyz[qh*3+0]-kp[0], ry = qxyz[qh*3+1]-kp[1], rz = qxyz[qh*3+2]-kp[2];
        #pragma unroll
        for (int kk=0;kk<4;kk++){
            int c0 = kk*32 + quad*8;
            #pragma unroll
            for (int h=0; h<2; ++h){
                float4 bb4 = *(const float4*)&s_b1[c0 + h*4];
                float4 wx4 = *(const float4*)&s_w1[c0 + h*4];
                float4 wy4 = *(const float4*)&s_w1[128 + c0 + h*4];
                float4 wz4 = *(const float4*)&s_w1[256 + c0 + h*4];
                float v0 = fmaxf(bb4.x + rx*wx4.x + ry*wy4.x + rz*wz4.x, 0.f);
                float v1 = fmaxf(bb4.y + rx*wx4.y + ry*wy4.y + rz*wz4.y, 0.f);
                float v2 = fmaxf(bb4.z + rx*wx4.z + ry*wy4.z + rz*wz4.z, 0.f);
                float v3 = fmaxf(bb4.w + rx*wx4.w + ry*wy4.w + rz*wz4.w, 0.f);
                h1f[kk][h*4+0] = (short)f2bf_u(v0);
                h1f[kk][h*4+1] = (short)f2bf_u(v1);
                h1f[kk][h*4+2] = (short)f2bf_u(v2);
                h1f[kk][h*4+3] = (short)f2bf_u(v3);
            }
        }
    }

    f32x4 acc[8];
    #pragma unroll
    for (int t=0;t<8;t++){ acc[t][0]=0.f; acc[t][1]=0.f; acc[t][2]=0.f; acc[t][3]=0.f; }
    #pragma unroll
    for (int kk=0;kk<4;kk++){
        #pragma unroll
        for (int t=0;t<8;t++){
            bf16x8 wf = *(const bf16x8*)&s_w[kk*4096 + (16*t + l15)*32 + quad*8];
            acc[t] = __builtin_amdgcn_mfma_f32_16x16x32_bf16(h1f[kk], wf, acc[t], 0, 0, 0);
        }
    }

    f32x4 dreg[8];
    #pragma unroll
    for (int t=0;t<8;t++){
        float b2v = s_b2[16*t + l15];
        #pragma unroll
        for (int r=0;r<4;r++) dreg[t][r] = fmaxf(acc[t][r] + b2v, 0.f);
    }

    bool val[4];
    #pragma unroll
    for (int r=0;r<4;r++){
        int j = s_j[w*16 + quad*4 + r];
        val[r] = (j >= 0);
    }
    const int qt = qbase + (quad >> 1);
    float ad[8];
    #pragma unroll
    for (int t=0;t<8;t++) ad[t] = adst[(size_t)qt*NC + 16*t + l15];

    __syncthreads();

    #pragma unroll
    for (int r = 0; r < 4; ++r)
        ((int4*)s_w)[r*512 + tid] = ((const int4*)wimg2)[r*512 + tid];

    {
        unsigned short* st = s_T + w*16*136;
        #pragma unroll
        for (int t=0;t<8;t++){
            #pragma unroll
            for (int r=0;r<4;r++){
                int o = (quad*4 + r)*136 + 16*t + l15;
                float sv = bf2f(st[o]);
                st[o] = f2bf_u(ad[t] - sv + dreg[t][r]);
            }
        }
    }
    __syncthreads();

    f32x4 acc2[8];
    #pragma unroll
    for (int t=0;t<8;t++){ acc2[t][0]=0.f; acc2[t][1]=0.f; acc2[t][2]=0.f; acc2[t][3]=0.f; }
    {
        const unsigned short* st = s_T + w*16*136;
        #pragma unroll
        for (int kk=0;kk<4;kk++){
            bf16x8 tf = *(const bf16x8*)&st[l15*136 + kk*32 + quad*8];
            #pragma unroll
            for (int t=0;t<8;t++){
                bf16x8 wf = *(const bf16x8*)&s_w[kk*4096 + (16*t + l15)*32 + quad*8];
                acc2[t] = __builtin_amdgcn_mfma_f32_16x16x32_bf16(tf, wf, acc2[t], 0, 0, 0);
            }
        }
    }

    float ex[8][4]; float dnm[8];
    #pragma unroll
    for (int t=0;t<8;t++){
        float ab = s_ab[16*t + l15];
        float s0 = val[0] ? fmaxf(acc2[t][0] + ab, 0.f) : -INFINITY;
        float s1 = val[1] ? fmaxf(acc2[t][1] + ab, 0.f) : -INFINITY;
        float s2 = val[2] ? fmaxf(acc2[t][2] + ab, 0.f) : -INFINITY;
        float s3 = val[3] ? fmaxf(acc2[t][3] + ab, 0.f) : -INFINITY;
        float mx = fmaxf(fmaxf(s0,s1), fmaxf(s2,s3));
        mx = fmaxf(mx, __shfl_xor(mx, 16));
        if (mx < -1e37f) mx = 0.f;
        ex[t][0] = __expf(s0 - mx);
        ex[t][1] = __expf(s1 - mx);
        ex[t][2] = __expf(s2 - mx);
        ex[t][3] = __expf(s3 - mx);
        float sm = ex[t][0]+ex[t][1]+ex[t][2]+ex[t][3];
        sm += __shfl_xor(sm, 16);
        dnm[t] = fmaxf(sm, 1e-12f);
    }

    float part[8];
    #pragma unroll
    for (int t=0;t<8;t++){
        float p = 0.f;
        #pragma unroll
        for (int r=0;r<4;r++){
            float vv = bf2f(s_V[(w*16 + quad*4 + r)*136 + 16*t + l15]);
            p += ex[t][r] * (vv + dreg[t][r]);
        }
        p += __shfl_xor(p, 16);
        part[t] = p / dnm[t];
    }

    float xln[8];
    float S = 0.f;
    #pragma unroll
    for (int t=0;t<8;t++){
        xln[t] = qfeat[(size_t)qt*NC + 16*t + l15] + part[t];
        S += xln[t];
    }
    #pragma unroll
    for (int m=1;m<=8;m<<=1) S += __shfl_xor(S, m);
    float mean = S * (1.f/128.f);
    float V = 0.f;
    #pragma unroll
    for (int t=0;t<8;t++){ float d = xln[t]-mean; V += d*d; }
    #pragma unroll
    for (int m=1;m<=8;m<<=1) V += __shfl_xor(V, m);
    float rstd = rsqrtf(V*(1.f/128.f) + 1e-5f);

    if ((quad & 1) == 0){
        #pragma unroll
        for (int t=0;t<8;t++){
            int c = 16*t + l15;
            out1[(size_t)qt*NC + c] = (xln[t]-mean)*rstd*s_g[c] + s_bb[c];
        }
    }
}

// ---------------------------------------------------------------------------
extern "C" void kernel_launch(void* const* d_in, const int* in_sizes, int n_in,
                              void* d_out, int out_size, void* d_ws, size_t ws_size,
                              hipStream_t stream)
{
    (void)in_sizes; (void)n_in; (void)out_size; (void)ws_size;
    const float* q_xyz   = (const float*)d_in[0];
    const float* q_feat  = (const float*)d_in[1];
    const float* kv_xyz  = (const float*)d_in[2];
    const float* kv_feat = (const float*)d_in[3];
    const unsigned char* kv_pad = (const unsigned char*)d_in[4];
    const float* pos_w1  = (const float*)d_in[5];
    const float* pos_b1  = (const float*)d_in[6];
    const float* pos_w2  = (const float*)d_in[7];
    const float* pos_b2  = (const float*)d_in[8];
    const float* attn_w  = (const float*)d_in[9];
    const float* attn_b  = (const float*)d_in[10];
    const float* lin_w   = (const float*)d_in[11];
    const float* lin_src_w = (const float*)d_in[12];
    const float* lin_dst_w = (const float*)d_in[13];
    const float* ln1_g   = (const float*)d_in[14];
    const float* ln1_b   = (const float*)d_in[15];
    const float* ffn_w1  = (const float*)d_in[16];
    const float* ffn_b1  = (const float*)d_in[17];
    const float* ffn_w2  = (const float*)d_in[18];
    const float* ffn_b2  = (const float*)d_in[19];
    const float* ln2_g   = (const float*)d_in[20];
    const float* ln2_b   = (const float*)d_in[21];

    float* ws    = (float*)d_ws;
    int*   idx   = (int*)d_ws;                                 // MQ*8 ints
    unsigned short* vs = (unsigned short*)(ws + 131072);       // [MQ,256] bf16 (v|s)
    float* adst  = ws + 131072 + 2*2097152;                    // [MQ,128] fp32
    float* out1  = adst + 2097152;                             // [MQ,128] fp32
    float* Hreg  = out1 + 2097152;                             // scratch region

    // grid-build scratch at Hreg start
    float4* reorder  = (float4*)Hreg;                // 256KB
    int* cellcnt   = (int*)(reorder + 16384);        // 8192
    int* cellfill  = cellcnt + 8192;                 // 8192
    int* cellstart = cellfill + 8192;                // 8193

    // weight images after grid scratch (offset 1MB into Hreg)
    unsigned short* imgb  = (unsigned short*)((char*)Hreg + (1u << 20));
    unsigned short* wimg1 = imgb;             // pos_w2    (16384)
    unsigned short* wimg2 = imgb + 16384;     // attn_w    (16384)
    unsigned short* wvs   = imgb + 32768;     // lin_w|lin_src_w (32768, Nd=256)
    unsigned short* wd    = imgb + 65536;     // lin_dst_w (16384)
    unsigned short* wf1   = imgb + 81920;     // ffn_w1    (65536, Nd=512)
    unsigned short* wf2   = imgb + 147456;    // ffn_w2    (65536)

    prep_all_kernel<<<dim3(896), dim3(256), 0, stream>>>(
        pos_w2, attn_w, lin_w, lin_src_w, lin_dst_w, ffn_w1, ffn_w2, imgb, cellcnt);

    grid_count_kernel<<<dim3(64), dim3(256), 0, stream>>>(kv_xyz, kv_pad, cellcnt);
    grid_scan_kernel<<<dim3(1), dim3(1024), 0, stream>>>(cellcnt, cellstart);
    grid_scatter_kernel<<<dim3(64), dim3(256), 0, stream>>>(kv_xyz, kv_pad, cellstart, cellfill, reorder);

    // merged: radius query (latency-bound) || lin3 GEMMs (MFMA-bound)
    query_lin3_kernel<<<dim3(MQ/32 + MQ/64 + MQ/64), dim3(256), 0, stream>>>(
        q_xyz, cellstart, reorder, idx,
        kv_feat, q_feat, wvs, wd, vs, adst);

    attn_mfma_kernel<<<dim3(MQ/16), dim3(512), 0, stream>>>(
        q_xyz, q_feat, kv_xyz,
        pos_w1, pos_b1, pos_b2, attn_b, ln1_g, ln1_b,
        wimg1, wimg2, idx, vs, adst, out1);

    ffn_fused_kernel<<<dim3(MQ/32), dim3(256), 0, stream>>>(
        out1, wf1, wf2, ffn_b1, ffn_b2, ln2_g, ln2_b, (float*)d_out);
}